// Round 5
// baseline (1122.999 us; speedup 1.0000x reference)
//
#include <hip/hip_runtime.h>
#include <math.h>

#define N_LEVELS 16
#define MAX_SIZE (1u << 19)   // 2^19 entries per level slab in `tables`

typedef float f2v __attribute__((ext_vector_type(2)));  // native 8B vector for nt builtins

struct Params {
    float res[N_LEVELS];
    unsigned int mask[N_LEVELS];
    int lstart[N_LEVELS + 1];   // phase p covers levels [lstart[p], lstart[p+1])
};

// ---------------------------------------------------------------------------
// Phase 1: phase-major gather. Grid = (blocks_per_point_range, n_phases).
// Resident-window phase lock keeps each phase's tables in the 4 MB per-XCD
// L2 (proven: FETCH 5.5 GB -> 0.42 GB). Now bound by TA address rate, so:
// x-pair trick: corners (2k,2k+1) share hy^hz; when ix is even,
// idx_hi = idx_lo^1 -> both corners live in one 16B-aligned float4 ->
// one dwordx4 address replaces two dword2 addresses. Odd-ix lanes do an
// exec-masked extra float2 gather (masked lanes issue no TA transactions).
// Avg gather addresses per (point,level): 8 -> 6.
// ---------------------------------------------------------------------------
__global__ __launch_bounds__(256) void hashgrid_phase_kernel(
    const float* __restrict__ x,
    const float* __restrict__ tables,
    float2* __restrict__ ws,          // [16][N] float2
    Params p, int N)
{
    int ph = blockIdx.y;
    int n = blockIdx.x * 256 + threadIdx.x;
    if (n >= N) return;

    float px = __builtin_nontemporal_load(x + (size_t)n * 3 + 0);
    float py = __builtin_nontemporal_load(x + (size_t)n * 3 + 1);
    float pz = __builtin_nontemporal_load(x + (size_t)n * 3 + 2);

    const unsigned int P2 = 2654435761u, P3 = 805459861u;

    int l0 = p.lstart[ph], l1 = p.lstart[ph + 1];
    for (int l = l0; l < l1; ++l) {
        float res = p.res[l];
        unsigned int mask = p.mask[l];
        const float* __restrict__ tabf =
            reinterpret_cast<const float*>(tables) + (size_t)l * MAX_SIZE * 2;
        const float2* __restrict__ tab = reinterpret_cast<const float2*>(tabf);

        // f32 semantics identical to reference: xs=x*res, xi=floor, xf=xs-xi
        float xs = px * res, ys = py * res, zs = pz * res;
        float fxi = floorf(xs), fyi = floorf(ys), fzi = floorf(zs);
        float wx1 = xs - fxi, wy1 = ys - fyi, wz1 = zs - fzi;
        float wx0 = 1.0f - wx1, wy0 = 1.0f - wy1, wz0 = 1.0f - wz1;

        unsigned int ix = (unsigned int)fxi;
        unsigned int iy = (unsigned int)fyi;
        unsigned int iz = (unsigned int)fzi;

        unsigned int hx0 = ix;       unsigned int hx1 = ix + 1u;
        unsigned int hy0 = iy * P2;  unsigned int hy1 = hy0 + P2;  // (iy+1)*P2 mod 2^32
        unsigned int hz0 = iz * P3;  unsigned int hz1 = hz0 + P3;

        // weights, same expression/order as reference
        float w[8];
#pragma unroll
        for (int c = 0; c < 8; ++c) {
            w[c] = (((c & 1) ? wx1 : wx0) * ((c & 2) ? wy1 : wy0)) * ((c & 4) ? wz1 : wz0);
        }

        // 4 yz-pairs; lo = x-corner, hi = x+1-corner
        unsigned int idx_lo[4], idx_hi[4];
#pragma unroll
        for (int k = 0; k < 4; ++k) {
            unsigned int hyz = ((k & 1) ? hy1 : hy0) ^ ((k & 2) ? hz1 : hz0);
            idx_lo[k] = (hx0 ^ hyz) & mask;
            idx_hi[k] = (hx1 ^ hyz) & mask;
        }
        bool even = (ix & 1u) == 0u;   // => idx_hi[k] == idx_lo[k]^1 (mask bit0 always set)

        // One 16B load per pair covers {idx_lo&~1, idx_lo|1}.
        float4 q[4];
#pragma unroll
        for (int k = 0; k < 4; ++k) {
            q[k] = *reinterpret_cast<const float4*>(
                tabf + (size_t)(idx_lo[k] & ~1u) * 2);
        }
        // Odd-ix lanes only: separate gather for the hi corner.
        float2 vh[4];
        if (!even) {
#pragma unroll
            for (int k = 0; k < 4; ++k) vh[k] = tab[idx_hi[k]];
        }

        float2 v[8];
#pragma unroll
        for (int k = 0; k < 4; ++k) {
            bool hi_half = (idx_lo[k] & 1u) != 0u;
            float2 lo    = hi_half ? make_float2(q[k].z, q[k].w)
                                   : make_float2(q[k].x, q[k].y);
            float2 other = hi_half ? make_float2(q[k].x, q[k].y)
                                   : make_float2(q[k].z, q[k].w);
            v[2 * k]     = lo;
            v[2 * k + 1] = even ? other : vh[k];
        }

        float accx = 0.0f, accy = 0.0f;
#pragma unroll
        for (int c = 0; c < 8; ++c) {   // sequential sum matches reference
            accx += v[c].x * w[c];
            accy += v[c].y * w[c];
        }

        f2v r; r.x = accx; r.y = accy;
        __builtin_nontemporal_store(
            r, reinterpret_cast<f2v*>(&ws[(size_t)l * N + n]));
    }
}

// ---------------------------------------------------------------------------
// Phase 2: transpose ws[l][n] -> out[n][l] via LDS tiles. Pure streaming,
// nontemporal both sides (no reuse).
// ---------------------------------------------------------------------------
__global__ __launch_bounds__(256) void transpose_kernel(
    const float2* __restrict__ ws,
    float2* __restrict__ out,
    int N)
{
    __shared__ float2 lds[N_LEVELS][257];   // +1 pad
    int tid = threadIdx.x;
    int n0 = blockIdx.x * 256;
    int n = n0 + tid;

#pragma unroll
    for (int l = 0; l < N_LEVELS; ++l) {
        if (n < N) {
            f2v v = __builtin_nontemporal_load(
                reinterpret_cast<const f2v*>(&ws[(size_t)l * N + n]));
            lds[l][tid] = make_float2(v.x, v.y);
        }
    }
    __syncthreads();

#pragma unroll
    for (int i = 0; i < 16; ++i) {
        int pn = i * 16 + (tid >> 4);   // point within tile
        int j  = tid & 15;              // level
        int np = n0 + pn;
        if (np < N) {
            float2 s = lds[j][pn];
            f2v v; v.x = s.x; v.y = s.y;
            __builtin_nontemporal_store(
                v, reinterpret_cast<f2v*>(&out[(size_t)np * 16 + j]));
        }
    }
}

// ---------------------------------------------------------------------------
// Fallback (original proven kernel): one thread per (point, level).
// ---------------------------------------------------------------------------
__global__ __launch_bounds__(256) void hashgrid_kernel(
    const float* __restrict__ x,
    const float* __restrict__ tables,
    float2* __restrict__ out,
    Params p, int total)
{
    int t = blockIdx.x * 256 + threadIdx.x;
    if (t >= total) return;
    int l = t & 15;
    int n = t >> 4;

    float res = p.res[l];
    unsigned int mask = p.mask[l];
    const float2* __restrict__ tab =
        reinterpret_cast<const float2*>(tables) + (size_t)l * MAX_SIZE;

    float px = x[n * 3 + 0];
    float py = x[n * 3 + 1];
    float pz = x[n * 3 + 2];

    float xs = px * res, ys = py * res, zs = pz * res;
    float fxi = floorf(xs), fyi = floorf(ys), fzi = floorf(zs);
    float wx1 = xs - fxi, wy1 = ys - fyi, wz1 = zs - fzi;
    float wx0 = 1.0f - wx1, wy0 = 1.0f - wy1, wz0 = 1.0f - wz1;

    unsigned int ix = (unsigned int)fxi;
    unsigned int iy = (unsigned int)fyi;
    unsigned int iz = (unsigned int)fzi;

    const unsigned int P2 = 2654435761u, P3 = 805459861u;
    unsigned int hx0 = ix;       unsigned int hx1 = ix + 1u;
    unsigned int hy0 = iy * P2;  unsigned int hy1 = hy0 + P2;
    unsigned int hz0 = iz * P3;  unsigned int hz1 = hz0 + P3;

    unsigned int hidx[8];
    float w[8];
#pragma unroll
    for (int c = 0; c < 8; ++c) {
        unsigned int hh = ((c & 1) ? hx1 : hx0)
                        ^ ((c & 2) ? hy1 : hy0)
                        ^ ((c & 4) ? hz1 : hz0);
        hidx[c] = hh & mask;
        w[c] = (((c & 1) ? wx1 : wx0) * ((c & 2) ? wy1 : wy0)) * ((c & 4) ? wz1 : wz0);
    }

    float2 v[8];
#pragma unroll
    for (int c = 0; c < 8; ++c) v[c] = tab[hidx[c]];

    float accx = 0.0f, accy = 0.0f;
#pragma unroll
    for (int c = 0; c < 8; ++c) {
        accx += v[c].x * w[c];
        accy += v[c].y * w[c];
    }

    out[t] = make_float2(accx, accy);
}

extern "C" void kernel_launch(void* const* d_in, const int* in_sizes, int n_in,
                              void* d_out, int out_size, void* d_ws, size_t ws_size,
                              hipStream_t stream) {
    const float* x      = (const float*)d_in[0];
    const float* tables = (const float*)d_in[1];
    float2* out         = (float2*)d_out;

    int N = in_sizes[0] / 3;

    // Replicate Python's level-constant computation bit-exactly with libm doubles.
    Params p;
    double b = exp((log(512.0) - log(16.0)) / 15.0);
    for (int l = 0; l < N_LEVELS; ++l) {
        double r = floor(16.0 * pow(b, (double)l));
        long long res = (long long)r;
        long long cube = res * res * res;
        long long sz = cube < (long long)(1u << 19) ? cube : (long long)(1u << 19);
        unsigned int pw = 1;
        while ((long long)pw < sz) pw <<= 1;
        p.res[l]  = (float)r;
        p.mask[l] = pw - 1u;
    }

    // Group levels into phases whose combined table bytes fit an L2 budget.
    const size_t BUDGET = (size_t)(7u << 19);   // 3.5 MB of 4 MB per-XCD L2
    int np = 0;
    size_t acc = 0;
    bool open = false;
    for (int l = 0; l < N_LEVELS; ++l) {
        size_t tb = ((size_t)p.mask[l] + 1) * sizeof(float2);
        if (open && acc + tb <= BUDGET) {
            acc += tb;
        } else {
            p.lstart[np++] = l;
            acc = tb;
            open = true;
        }
    }
    p.lstart[np] = N_LEVELS;

    size_t ws_needed = (size_t)N * N_LEVELS * sizeof(float2);  // 256 MB at N=2M
    int bpl = (N + 255) / 256;

    if (ws_size >= ws_needed) {
        dim3 grid1(bpl, np, 1);
        hashgrid_phase_kernel<<<grid1, 256, 0, stream>>>(
            x, tables, (float2*)d_ws, p, N);
        transpose_kernel<<<bpl, 256, 0, stream>>>(
            (const float2*)d_ws, out, N);
    } else {
        // Workspace too small: original fused kernel (known-good, 1789 us).
        int total = N * N_LEVELS;
        int blocks = (total + 255) / 256;
        hashgrid_kernel<<<blocks, 256, 0, stream>>>(x, tables, out, p, total);
    }
}

// Round 6
// 963.702 us; speedup vs baseline: 1.1653x; 1.1653x over previous
//
#include <hip/hip_runtime.h>
#include <math.h>

#define N_LEVELS 16
#define MAX_SIZE (1u << 19)   // 2^19 entries per level slab in `tables`
#define FIRST_FINE 6          // levels 0..5 (tables sum 2MB) computed in pass 2

typedef float f2v __attribute__((ext_vector_type(2)));  // native 8B vector for nt builtins

struct Params {
    float res[N_LEVELS];
    unsigned int mask[N_LEVELS];
};

// Shared per-level math (bit-identical to reference):
//   xs = x*res (f32), xi = floor, xf = xs - xi; corner c: bit0->x, bit1->y, bit2->z
//   w = ((wx*wy)*wz); idx = (hx ^ hy ^ hz) & mask; sum over c = 0..7 sequentially.
__device__ __forceinline__ float2 level_encode(
    float px, float py, float pz, float res, unsigned int mask,
    const float2* __restrict__ tab)
{
    const unsigned int P2 = 2654435761u, P3 = 805459861u;
    float xs = px * res, ys = py * res, zs = pz * res;
    float fxi = floorf(xs), fyi = floorf(ys), fzi = floorf(zs);
    float wx1 = xs - fxi, wy1 = ys - fyi, wz1 = zs - fzi;
    float wx0 = 1.0f - wx1, wy0 = 1.0f - wy1, wz0 = 1.0f - wz1;

    unsigned int ix = (unsigned int)fxi;
    unsigned int iy = (unsigned int)fyi;
    unsigned int iz = (unsigned int)fzi;

    unsigned int hx0 = ix;       unsigned int hx1 = ix + 1u;
    unsigned int hy0 = iy * P2;  unsigned int hy1 = hy0 + P2;   // (iy+1)*P2 mod 2^32
    unsigned int hz0 = iz * P3;  unsigned int hz1 = hz0 + P3;

    unsigned int hidx[8];
    float w[8];
#pragma unroll
    for (int c = 0; c < 8; ++c) {
        unsigned int hh = ((c & 1) ? hx1 : hx0)
                        ^ ((c & 2) ? hy1 : hy0)
                        ^ ((c & 4) ? hz1 : hz0);
        hidx[c] = hh & mask;
        w[c] = (((c & 1) ? wx1 : wx0) * ((c & 2) ? wy1 : wy0)) * ((c & 4) ? wz1 : wz0);
    }

    // Issue all 8 gathers before use -> 8 outstanding loads.
    float2 v[8];
#pragma unroll
    for (int c = 0; c < 8; ++c) v[c] = tab[hidx[c]];

    float accx = 0.0f, accy = 0.0f;
#pragma unroll
    for (int c = 0; c < 8; ++c) {     // sequential sum matches reference
        accx += v[c].x * w[c];
        accy += v[c].y * w[c];
    }
    return make_float2(accx, accy);
}

// ---------------------------------------------------------------------------
// Pass 1: fine levels (6..15), one level per blockIdx.y. Dispatch order makes
// the resident window cover one level -> its <=4MB table lives in each XCD's
// L2 (proven: FETCH 5.5GB -> 0.42GB). Gather time tracks TCP-requested bytes
// (R4/R5 A/B), so this kernel carries only the 10 fine levels: 840 B/point
// vs 1284 before. Streams use nt hints. ws[l-6][n], coalesced.
// ---------------------------------------------------------------------------
__global__ __launch_bounds__(256) void hashgrid_fine_kernel(
    const float* __restrict__ x,
    const float* __restrict__ tables,
    float2* __restrict__ ws,          // [10][N] float2, compact fine slab
    Params p, int N)
{
    int l = FIRST_FINE + blockIdx.y;
    int n = blockIdx.x * 256 + threadIdx.x;
    if (n >= N) return;

    float px = __builtin_nontemporal_load(x + (size_t)n * 3 + 0);
    float py = __builtin_nontemporal_load(x + (size_t)n * 3 + 1);
    float pz = __builtin_nontemporal_load(x + (size_t)n * 3 + 2);

    const float2* __restrict__ tab =
        reinterpret_cast<const float2*>(tables) + (size_t)l * MAX_SIZE;

    float2 r = level_encode(px, py, pz, p.res[l], p.mask[l], tab);

    f2v rv; rv.x = r.x; rv.y = r.y;
    __builtin_nontemporal_store(
        rv, reinterpret_cast<f2v*>(&ws[(size_t)(l - FIRST_FINE) * N + n]));
}

// ---------------------------------------------------------------------------
// Pass 2: compute coarse levels 0..5 (tables total 2MB -> L2-resident on
// every XCD for the whole pass; their gather cost hides under this kernel's
// HBM streaming) + read fine results from ws + LDS-transpose to out[n][16].
// ---------------------------------------------------------------------------
__global__ __launch_bounds__(256) void coarse_transpose_kernel(
    const float* __restrict__ x,
    const float* __restrict__ tables,
    const float2* __restrict__ ws,
    float2* __restrict__ out,
    Params p, int N)
{
    __shared__ float2 lds[N_LEVELS][257];   // +1 pad
    int tid = threadIdx.x;
    int n0 = blockIdx.x * 256;
    int n = n0 + tid;

    if (n < N) {
        // Issue the 10 fine ws loads first (long latency, independent).
        f2v wsr[10];
#pragma unroll
        for (int l = FIRST_FINE; l < N_LEVELS; ++l) {
            wsr[l - FIRST_FINE] = __builtin_nontemporal_load(
                reinterpret_cast<const f2v*>(&ws[(size_t)(l - FIRST_FINE) * N + n]));
        }

        float px = __builtin_nontemporal_load(x + (size_t)n * 3 + 0);
        float py = __builtin_nontemporal_load(x + (size_t)n * 3 + 1);
        float pz = __builtin_nontemporal_load(x + (size_t)n * 3 + 2);

        // Coarse levels: plain (cached) loads -- tables stay L2/L1 resident.
#pragma unroll
        for (int l = 0; l < FIRST_FINE; ++l) {
            const float2* __restrict__ tab =
                reinterpret_cast<const float2*>(tables) + (size_t)l * MAX_SIZE;
            lds[l][tid] = level_encode(px, py, pz, p.res[l], p.mask[l], tab);
        }
#pragma unroll
        for (int l = FIRST_FINE; l < N_LEVELS; ++l) {
            lds[l][tid] = make_float2(wsr[l - FIRST_FINE].x, wsr[l - FIRST_FINE].y);
        }
    }
    __syncthreads();

#pragma unroll
    for (int i = 0; i < 16; ++i) {
        int pn = i * 16 + (tid >> 4);   // point within tile
        int j  = tid & 15;              // level
        int np = n0 + pn;
        if (np < N) {
            float2 s = lds[j][pn];
            f2v v; v.x = s.x; v.y = s.y;
            __builtin_nontemporal_store(
                v, reinterpret_cast<f2v*>(&out[(size_t)np * 16 + j]));
        }
    }
}

// ---------------------------------------------------------------------------
// Fallback (original proven kernel): one thread per (point, level).
// ---------------------------------------------------------------------------
__global__ __launch_bounds__(256) void hashgrid_kernel(
    const float* __restrict__ x,
    const float* __restrict__ tables,
    float2* __restrict__ out,
    Params p, int total)
{
    int t = blockIdx.x * 256 + threadIdx.x;
    if (t >= total) return;
    int l = t & 15;
    int n = t >> 4;

    const float2* __restrict__ tab =
        reinterpret_cast<const float2*>(tables) + (size_t)l * MAX_SIZE;

    float px = x[n * 3 + 0];
    float py = x[n * 3 + 1];
    float pz = x[n * 3 + 2];

    out[t] = level_encode(px, py, pz, p.res[l], p.mask[l], tab);
}

extern "C" void kernel_launch(void* const* d_in, const int* in_sizes, int n_in,
                              void* d_out, int out_size, void* d_ws, size_t ws_size,
                              hipStream_t stream) {
    const float* x      = (const float*)d_in[0];
    const float* tables = (const float*)d_in[1];
    float2* out         = (float2*)d_out;

    int N = in_sizes[0] / 3;

    // Replicate Python's level-constant computation bit-exactly with libm doubles.
    Params p;
    double b = exp((log(512.0) - log(16.0)) / 15.0);
    for (int l = 0; l < N_LEVELS; ++l) {
        double r = floor(16.0 * pow(b, (double)l));
        long long res = (long long)r;
        long long cube = res * res * res;
        long long sz = cube < (long long)(1u << 19) ? cube : (long long)(1u << 19);
        unsigned int pw = 1;
        while ((long long)pw < sz) pw <<= 1;
        p.res[l]  = (float)r;
        p.mask[l] = pw - 1u;
    }

    size_t ws_needed = (size_t)N * (N_LEVELS - FIRST_FINE) * sizeof(float2);  // 160 MB at N=2M
    int bpl = (N + 255) / 256;

    if (ws_size >= ws_needed) {
        dim3 grid1(bpl, N_LEVELS - FIRST_FINE, 1);
        hashgrid_fine_kernel<<<grid1, 256, 0, stream>>>(
            x, tables, (float2*)d_ws, p, N);
        coarse_transpose_kernel<<<bpl, 256, 0, stream>>>(
            x, tables, (const float2*)d_ws, out, p, N);
    } else {
        // Workspace too small: original fused kernel (known-good, 1789 us).
        int total = N * N_LEVELS;
        int blocks = (total + 255) / 256;
        hashgrid_kernel<<<blocks, 256, 0, stream>>>(x, tables, out, p, total);
    }
}

// Round 7
// 938.067 us; speedup vs baseline: 1.1971x; 1.0273x over previous
//
#include <hip/hip_runtime.h>
#include <math.h>

#define N_LEVELS 16
#define MAX_SIZE (1u << 19)   // 2^19 entries per level slab in `tables`
#define FIRST_FINE 6          // levels 0..5 computed in pass 2

typedef float f2v __attribute__((ext_vector_type(2)));  // native 8B vector for nt builtins

struct Params {
    float res[N_LEVELS];
    unsigned int mask[N_LEVELS];
};

// Corner prep, bit-identical to reference math:
//   xs = x*res (f32), xi = floor, xf = xs - xi; corner c: bit0->x, bit1->y, bit2->z
//   w = ((wx*wy)*wz); idx = (hx ^ hy ^ hz) & mask
__device__ __forceinline__ void hash_prep(
    float px, float py, float pz, float res, unsigned int mask,
    unsigned int (&hidx)[8], float (&w)[8])
{
    const unsigned int P2 = 2654435761u, P3 = 805459861u;
    float xs = px * res, ys = py * res, zs = pz * res;
    float fxi = floorf(xs), fyi = floorf(ys), fzi = floorf(zs);
    float wx1 = xs - fxi, wy1 = ys - fyi, wz1 = zs - fzi;
    float wx0 = 1.0f - wx1, wy0 = 1.0f - wy1, wz0 = 1.0f - wz1;

    unsigned int ix = (unsigned int)fxi;
    unsigned int iy = (unsigned int)fyi;
    unsigned int iz = (unsigned int)fzi;

    unsigned int hx0 = ix;       unsigned int hx1 = ix + 1u;
    unsigned int hy0 = iy * P2;  unsigned int hy1 = hy0 + P2;   // (iy+1)*P2 mod 2^32
    unsigned int hz0 = iz * P3;  unsigned int hz1 = hz0 + P3;

#pragma unroll
    for (int c = 0; c < 8; ++c) {
        unsigned int hh = ((c & 1) ? hx1 : hx0)
                        ^ ((c & 2) ? hy1 : hy0)
                        ^ ((c & 4) ? hz1 : hz0);
        hidx[c] = hh & mask;
        w[c] = (((c & 1) ? wx1 : wx0) * ((c & 2) ? wy1 : wy0)) * ((c & 4) ? wz1 : wz0);
    }
}

__device__ __forceinline__ float2 weighted_sum(const float2 (&v)[8], const float (&w)[8])
{
    float accx = 0.0f, accy = 0.0f;
#pragma unroll
    for (int c = 0; c < 8; ++c) {     // sequential sum matches reference
        accx += v[c].x * w[c];
        accy += v[c].y * w[c];
    }
    return make_float2(accx, accy);
}

// Reference-identical single-(point,level) encode (used by fallback kernel).
__device__ __forceinline__ float2 level_encode(
    float px, float py, float pz, float res, unsigned int mask,
    const float2* __restrict__ tab)
{
    unsigned int hidx[8];
    float w[8];
    hash_prep(px, py, pz, res, mask, hidx, w);
    float2 v[8];
#pragma unroll
    for (int c = 0; c < 8; ++c) v[c] = tab[hidx[c]];
    return weighted_sum(v, w);
}

// ---------------------------------------------------------------------------
// Pass 1: fine levels (6..15), one level per blockIdx.y (phase-locked L2
// residency: FETCH 5.5GB -> 0.4GB proven). R6 showed 0.54 fills/cy/CU at
// VALUBusy 8% / occ 84% -> latency-bound, not throughput-bound. So: TWO
// points per thread = 16 independent gathers in flight (VGPR ~60, still
// 8 waves/SIMD). Streams keep nt hints. ws[l-6][n], coalesced.
// ---------------------------------------------------------------------------
__global__ __launch_bounds__(256) void hashgrid_fine_kernel(
    const float* __restrict__ x,
    const float* __restrict__ tables,
    float2* __restrict__ ws,          // [10][N] float2, compact fine slab
    Params p, int N)
{
    int l = FIRST_FINE + blockIdx.y;
    int n0 = blockIdx.x * 512 + threadIdx.x;
    int n1 = n0 + 256;
    if (n0 >= N) return;
    bool has1 = n1 < N;

    float res = p.res[l];
    unsigned int mask = p.mask[l];
    const float2* __restrict__ tab =
        reinterpret_cast<const float2*>(tables) + (size_t)l * MAX_SIZE;

    float px0 = __builtin_nontemporal_load(x + (size_t)n0 * 3 + 0);
    float py0 = __builtin_nontemporal_load(x + (size_t)n0 * 3 + 1);
    float pz0 = __builtin_nontemporal_load(x + (size_t)n0 * 3 + 2);
    float px1 = 0.f, py1 = 0.f, pz1 = 0.f;
    if (has1) {
        px1 = __builtin_nontemporal_load(x + (size_t)n1 * 3 + 0);
        py1 = __builtin_nontemporal_load(x + (size_t)n1 * 3 + 1);
        pz1 = __builtin_nontemporal_load(x + (size_t)n1 * 3 + 2);
    }

    unsigned int i0[8], i1[8];
    float w0[8], w1[8];
    hash_prep(px0, py0, pz0, res, mask, i0, w0);
    hash_prep(px1, py1, pz1, res, mask, i1, w1);

    // Issue all 16 gathers before any use (point-1 gathers exec-masked in tail).
    float2 v0[8], v1[8];
#pragma unroll
    for (int c = 0; c < 8; ++c) v0[c] = tab[i0[c]];
    if (has1) {
#pragma unroll
        for (int c = 0; c < 8; ++c) v1[c] = tab[i1[c]];
    }

    float2 r0 = weighted_sum(v0, w0);
    f2v rv0; rv0.x = r0.x; rv0.y = r0.y;
    __builtin_nontemporal_store(
        rv0, reinterpret_cast<f2v*>(&ws[(size_t)(l - FIRST_FINE) * N + n0]));
    if (has1) {
        float2 r1 = weighted_sum(v1, w1);
        f2v rv1; rv1.x = r1.x; rv1.y = r1.y;
        __builtin_nontemporal_store(
            rv1, reinterpret_cast<f2v*>(&ws[(size_t)(l - FIRST_FINE) * N + n1]));
    }
}

// ---------------------------------------------------------------------------
// Pass 2: coarse levels 0..5 (tables ~3.9MB, L2-resident) + ws read +
// LDS-transpose to out[n][16]. Coarse levels batched in PAIRS: issue 16
// gathers before consuming any (R6 did 8-issue/8-consume per level).
// ---------------------------------------------------------------------------
__global__ __launch_bounds__(256) void coarse_transpose_kernel(
    const float* __restrict__ x,
    const float* __restrict__ tables,
    const float2* __restrict__ ws,
    float2* __restrict__ out,
    Params p, int N)
{
    __shared__ float2 lds[N_LEVELS][257];   // +1 pad
    int tid = threadIdx.x;
    int n0 = blockIdx.x * 256;
    int n = n0 + tid;

    if (n < N) {
        // Issue the 10 fine ws loads first (long latency, independent).
        f2v wsr[10];
#pragma unroll
        for (int l = FIRST_FINE; l < N_LEVELS; ++l) {
            wsr[l - FIRST_FINE] = __builtin_nontemporal_load(
                reinterpret_cast<const f2v*>(&ws[(size_t)(l - FIRST_FINE) * N + n]));
        }

        float px = __builtin_nontemporal_load(x + (size_t)n * 3 + 0);
        float py = __builtin_nontemporal_load(x + (size_t)n * 3 + 1);
        float pz = __builtin_nontemporal_load(x + (size_t)n * 3 + 2);

        // Coarse levels in pairs: prep both, issue 16 gathers, then consume.
#pragma unroll
        for (int g = 0; g < FIRST_FINE; g += 2) {
            const float2* __restrict__ tabA =
                reinterpret_cast<const float2*>(tables) + (size_t)g * MAX_SIZE;
            const float2* __restrict__ tabB =
                reinterpret_cast<const float2*>(tables) + (size_t)(g + 1) * MAX_SIZE;

            unsigned int iA[8], iB[8];
            float wA[8], wB[8];
            hash_prep(px, py, pz, p.res[g],     p.mask[g],     iA, wA);
            hash_prep(px, py, pz, p.res[g + 1], p.mask[g + 1], iB, wB);

            float2 vA[8], vB[8];
#pragma unroll
            for (int c = 0; c < 8; ++c) vA[c] = tabA[iA[c]];
#pragma unroll
            for (int c = 0; c < 8; ++c) vB[c] = tabB[iB[c]];

            lds[g][tid]     = weighted_sum(vA, wA);
            lds[g + 1][tid] = weighted_sum(vB, wB);
        }

#pragma unroll
        for (int l = FIRST_FINE; l < N_LEVELS; ++l) {
            lds[l][tid] = make_float2(wsr[l - FIRST_FINE].x, wsr[l - FIRST_FINE].y);
        }
    }
    __syncthreads();

#pragma unroll
    for (int i = 0; i < 16; ++i) {
        int pn = i * 16 + (tid >> 4);   // point within tile
        int j  = tid & 15;              // level
        int np = n0 + pn;
        if (np < N) {
            float2 s = lds[j][pn];
            f2v v; v.x = s.x; v.y = s.y;
            __builtin_nontemporal_store(
                v, reinterpret_cast<f2v*>(&out[(size_t)np * 16 + j]));
        }
    }
}

// ---------------------------------------------------------------------------
// Fallback (original proven kernel): one thread per (point, level).
// ---------------------------------------------------------------------------
__global__ __launch_bounds__(256) void hashgrid_kernel(
    const float* __restrict__ x,
    const float* __restrict__ tables,
    float2* __restrict__ out,
    Params p, int total)
{
    int t = blockIdx.x * 256 + threadIdx.x;
    if (t >= total) return;
    int l = t & 15;
    int n = t >> 4;

    const float2* __restrict__ tab =
        reinterpret_cast<const float2*>(tables) + (size_t)l * MAX_SIZE;

    float px = x[n * 3 + 0];
    float py = x[n * 3 + 1];
    float pz = x[n * 3 + 2];

    out[t] = level_encode(px, py, pz, p.res[l], p.mask[l], tab);
}

extern "C" void kernel_launch(void* const* d_in, const int* in_sizes, int n_in,
                              void* d_out, int out_size, void* d_ws, size_t ws_size,
                              hipStream_t stream) {
    const float* x      = (const float*)d_in[0];
    const float* tables = (const float*)d_in[1];
    float2* out         = (float2*)d_out;

    int N = in_sizes[0] / 3;

    // Replicate Python's level-constant computation bit-exactly with libm doubles.
    Params p;
    double b = exp((log(512.0) - log(16.0)) / 15.0);
    for (int l = 0; l < N_LEVELS; ++l) {
        double r = floor(16.0 * pow(b, (double)l));
        long long res = (long long)r;
        long long cube = res * res * res;
        long long sz = cube < (long long)(1u << 19) ? cube : (long long)(1u << 19);
        unsigned int pw = 1;
        while ((long long)pw < sz) pw <<= 1;
        p.res[l]  = (float)r;
        p.mask[l] = pw - 1u;
    }

    size_t ws_needed = (size_t)N * (N_LEVELS - FIRST_FINE) * sizeof(float2);  // 160 MB at N=2M
    int bpl = (N + 255) / 256;

    if (ws_size >= ws_needed) {
        int bpl2 = (N + 511) / 512;   // 2 points per thread in pass 1
        dim3 grid1(bpl2, N_LEVELS - FIRST_FINE, 1);
        hashgrid_fine_kernel<<<grid1, 256, 0, stream>>>(
            x, tables, (float2*)d_ws, p, N);
        coarse_transpose_kernel<<<bpl, 256, 0, stream>>>(
            x, tables, (const float2*)d_ws, out, p, N);
    } else {
        // Workspace too small: original fused kernel (known-good, 1789 us).
        int total = N * N_LEVELS;
        int blocks = (total + 255) / 256;
        hashgrid_kernel<<<blocks, 256, 0, stream>>>(x, tables, out, p, total);
    }
}